// Round 1
// baseline (727.403 us; speedup 1.0000x reference)
//
#include <hip/hip_runtime.h>
#include <stdint.h>

// Problem constants (reference: B=128, S=1024, D=1024)
#define BB 128
#define SS 1024
#define DD 1024
#define MT 128          // M-tile per block
#define BK 64           // K-chunk per iteration
#define LDT 72          // padded LDS row stride in shorts (144 B: breaks 32-bank aliasing)

typedef __attribute__((ext_vector_type(4))) float f32x4;
typedef __attribute__((ext_vector_type(8))) short s16x8;

// ---------------- kernel 1: lens[b] = clip(sum(mask[b,:]),1), num_nodes = sum(lens) -------------
__global__ __launch_bounds__(256) void lens_kernel(const int* __restrict__ mask,
                                                   int* __restrict__ nn_lens) {
    const int b = blockIdx.x;
    const int t = threadIdx.x;
    const int* row = mask + b * SS;
    int s = row[t] + row[t + 256] + row[t + 512] + row[t + 768];
    #pragma unroll
    for (int off = 32; off > 0; off >>= 1) s += __shfl_down(s, off, 64);
    __shared__ int red[4];
    const int wid = t >> 6, lane = t & 63;
    if (lane == 0) red[wid] = s;
    __syncthreads();
    if (t == 0) {
        int tot = red[0] + red[1] + red[2] + red[3];
        if (tot < 1) tot = 1;
        nn_lens[1 + b] = tot;
        atomicAdd(&nn_lens[0], tot);
    }
}

// round-half-up fp32->bf16 pair pack: 3 VALU per 2 elements
__device__ __forceinline__ unsigned pack_bf(float lo, float hi) {
    unsigned ul = __builtin_bit_cast(unsigned, lo) + 0x8000u;
    unsigned uh = __builtin_bit_cast(unsigned, hi) + 0x8000u;
    // bytes [7,6,3,2] of {uh:ul} -> (uh & 0xFFFF0000) | (ul >> 16)
    return __builtin_amdgcn_perm(uh, ul, 0x07060302u);
}

// ---------------- kernel 2: GEMM (bf16 MFMA) + softplus epilogue + masked reduction -------------
__global__ __launch_bounds__(256, 4) void mi_kernel(const float* __restrict__ A,   // [B*S, D]
                                                    const float* __restrict__ Bm,  // [B, D]
                                                    const int* __restrict__ nn_lens,
                                                    float* __restrict__ out) {
    __shared__ short lds[2 * MT * LDT];
    short* As = lds;
    short* Bs = lds + MT * LDT;

    const int tid  = threadIdx.x;
    const int lane = tid & 63;
    const int wid  = tid >> 6;
    const int wm   = (wid >> 1) * 64;   // wave M offset within tile
    const int wn   = (wid & 1) * 64;    // wave N offset within tile
    const int ln15 = lane & 15;
    const int quad = lane >> 4;

    const int blk    = blockIdx.x;
    const size_t m0  = (size_t)blk * MT;
    const int b_idx  = blk >> 3;          // graph index of this block's rows (S/MT = 8)
    const int s_base = (blk & 7) * MT;    // sequence offset of row 0

    // staging: thread handles 8 consecutive floats (2 float4) -> 1 ds_write_b128
    const int srow = tid >> 3;   // 0..31 (4 passes of 32 rows cover 128)
    const int schk = tid & 7;    // 8-float chunk within a 64-float K-slab

    const float* Abase = A  + (m0 + srow) * (size_t)DD + schk * 8;
    const float* Bbase = Bm + (size_t)srow * DD + schk * 8;
    short* As_w = As + srow * LDT + schk * 8;
    short* Bs_w = Bs + srow * LDT + schk * 8;

    f32x4 acc[4][4];
    #pragma unroll
    for (int i = 0; i < 4; i++)
        #pragma unroll
        for (int j = 0; j < 4; j++) acc[i][j] = (f32x4)0.f;

    for (int kt = 0; kt < DD / BK; kt++) {
        const int k0 = kt * BK;
        #pragma unroll
        for (int p = 0; p < 4; p++) {
            const float* ga = Abase + (size_t)(p * 32) * DD + k0;
            const float* gb = Bbase + (size_t)(p * 32) * DD + k0;
            f32x4 a0 = *(const f32x4*)(ga);
            f32x4 a1 = *(const f32x4*)(ga + 4);
            f32x4 b0 = *(const f32x4*)(gb);
            f32x4 b1 = *(const f32x4*)(gb + 4);
            uint4 pa, pb;
            pa.x = pack_bf(a0.x, a0.y);  pa.y = pack_bf(a0.z, a0.w);
            pa.z = pack_bf(a1.x, a1.y);  pa.w = pack_bf(a1.z, a1.w);
            pb.x = pack_bf(b0.x, b0.y);  pb.y = pack_bf(b0.z, b0.w);
            pb.z = pack_bf(b1.x, b1.y);  pb.w = pack_bf(b1.z, b1.w);
            *(uint4*)(As_w + p * 32 * LDT) = pa;
            *(uint4*)(Bs_w + p * 32 * LDT) = pb;
        }
        __syncthreads();
        #pragma unroll
        for (int ks = 0; ks < 2; ks++) {
            const int ko = ks * 32 + quad * 8;
            s16x8 af[4], bf[4];
            #pragma unroll
            for (int i = 0; i < 4; i++)
                af[i] = *(const s16x8*)(As + (wm + i * 16 + ln15) * LDT + ko);
            #pragma unroll
            for (int j = 0; j < 4; j++)
                bf[j] = *(const s16x8*)(Bs + (wn + j * 16 + ln15) * LDT + ko);
            #pragma unroll
            for (int i = 0; i < 4; i++)
                #pragma unroll
                for (int j = 0; j < 4; j++)
                    acc[i][j] = __builtin_amdgcn_mfma_f32_16x16x32_bf16(af[i], bf[j], acc[i][j], 0, 0, 0);
        }
        __syncthreads();
    }

    // ---- fused epilogue: JSD terms, masked ----
    const int num_nodes = nn_lens[0];
    const int len_b     = nn_lens[1 + b_idx];
    const float LOG2f = 0.6931471805599453f;

    float pos_sum = 0.f, neg_sum = 0.f;
    #pragma unroll
    for (int i = 0; i < 4; i++) {
        #pragma unroll
        for (int r = 0; r < 4; r++) {
            const int s = s_base + wm + i * 16 + quad * 4 + r;       // C/D row = quad*4+reg
            const bool valid = (s < len_b);
            #pragma unroll
            for (int j = 0; j < 4; j++) {
                const int n = wn + j * 16 + ln15;                    // C/D col = lane&15
                const float x = acc[i][j][r];
                // sp = softplus(-x), numerically stable
                const float e  = __expf(-fabsf(x));
                const float sp = fmaxf(-x, 0.f) + __logf(1.f + e);
                if (valid) {
                    if (n == b_idx) pos_sum += LOG2f - sp;           // Ep
                    else            neg_sum += sp + x - LOG2f;       // Eq
                }
            }
        }
    }

    // block reduction + one atomic per block
    #pragma unroll
    for (int off = 32; off > 0; off >>= 1) {
        pos_sum += __shfl_down(pos_sum, off, 64);
        neg_sum += __shfl_down(neg_sum, off, 64);
    }
    __syncthreads();                     // LDS tiles no longer needed
    __shared__ float red[8];
    if (lane == 0) { red[wid] = pos_sum; red[4 + wid] = neg_sum; }
    __syncthreads();
    if (tid == 0) {
        const float p  = red[0] + red[1] + red[2] + red[3];
        const float ng = red[4] + red[5] + red[6] + red[7];
        const float nn = (float)num_nodes;
        const float contrib = ng / (nn * (float)(BB - 1)) - p / nn;
        atomicAdd(out, contrib);
    }
}

extern "C" void kernel_launch(void* const* d_in, const int* in_sizes, int n_in,
                              void* d_out, int out_size, void* d_ws, size_t ws_size,
                              hipStream_t stream) {
    const float* seq  = (const float*)d_in[0];   // [128,1024,1024] fp32
    const float* ctx  = (const float*)d_in[1];   // [128,1024] fp32
    const int*   mask = (const int*)d_in[2];     // [128,1024] int32
    int* nn_lens = (int*)d_ws;                   // [0]=num_nodes, [1..128]=lens

    hipMemsetAsync(d_out, 0, sizeof(float), stream);
    hipMemsetAsync(d_ws, 0, sizeof(int), stream);

    lens_kernel<<<BB, 256, 0, stream>>>(mask, nn_lens);
    mi_kernel<<<(BB * SS) / MT, 256, 0, stream>>>(seq, ctx, nn_lens, (float*)d_out);
}

// Round 2
// 725.471 us; speedup vs baseline: 1.0027x; 1.0027x over previous
//
#include <hip/hip_runtime.h>
#include <stdint.h>

// Problem constants (reference: B=128, S=1024, D=1024)
#define BB 128
#define SS 1024
#define DD 1024
#define MT 128          // M-tile per block
#define BK 64           // K-chunk per iteration
#define LDT 72          // padded LDS row stride in shorts (144 B: spreads b128 reads over all banks)

typedef __attribute__((ext_vector_type(4))) float f32x4;
typedef __attribute__((ext_vector_type(8))) short s16x8;

// ---------------- kernel 1: lens[b] = clip(sum(mask[b,:]),1), num_nodes = sum(lens) -------------
__global__ __launch_bounds__(256) void lens_kernel(const int* __restrict__ mask,
                                                   int* __restrict__ nn_lens) {
    const int b = blockIdx.x;
    const int t = threadIdx.x;
    const int* row = mask + b * SS;
    int s = row[t] + row[t + 256] + row[t + 512] + row[t + 768];
    #pragma unroll
    for (int off = 32; off > 0; off >>= 1) s += __shfl_down(s, off, 64);
    __shared__ int red[4];
    const int wid = t >> 6, lane = t & 63;
    if (lane == 0) red[wid] = s;
    __syncthreads();
    if (t == 0) {
        int tot = red[0] + red[1] + red[2] + red[3];
        if (tot < 1) tot = 1;
        nn_lens[1 + b] = tot;
        atomicAdd(&nn_lens[0], tot);
    }
}

// round-half-up fp32->bf16 pair pack: 3 VALU per 2 elements
__device__ __forceinline__ unsigned pack_bf(float lo, float hi) {
    unsigned ul = __builtin_bit_cast(unsigned, lo) + 0x8000u;
    unsigned uh = __builtin_bit_cast(unsigned, hi) + 0x8000u;
    return __builtin_amdgcn_perm(uh, ul, 0x07060302u);
}

// ---------------- kernel 2: GEMM (bf16 MFMA) + softplus epilogue + masked reduction -------------
// launch_bounds(256,2): 256-VGPR budget. (256,4) forced 128 VGPRs -> ~50-reg scratch spill in the
// K-loop -> 727us. This kernel wants ~180 VGPRs (64 acc + 32 frag + staging + addr).
__global__ __launch_bounds__(256, 2) void mi_kernel(const float* __restrict__ A,   // [B*S, D]
                                                    const float* __restrict__ Bm,  // [B, D]
                                                    const int* __restrict__ nn_lens,
                                                    float* __restrict__ out) {
    __shared__ short lds[2 * MT * LDT];
    short* As = lds;
    short* Bs = lds + MT * LDT;

    const int tid  = threadIdx.x;
    const int lane = tid & 63;
    const int wid  = tid >> 6;
    const int wm   = (wid >> 1) * 64;   // wave M offset within tile
    const int wn   = (wid & 1) * 64;    // wave N offset within tile
    const int ln15 = lane & 15;
    const int quad = lane >> 4;

    const int blk    = blockIdx.x;
    const size_t m0  = (size_t)blk * MT;
    const int b_idx  = blk >> 3;          // graph index of this block's rows (S/MT = 8)
    const int s_base = (blk & 7) * MT;    // sequence offset of row 0

    // staging: thread handles 8 consecutive floats (2 float4) -> 1 ds_write_b128
    const int srow = tid >> 3;   // 0..31 (4 passes of 32 rows cover 128)
    const int schk = tid & 7;    // 8-float chunk within a 64-float K-slab

    const float* Abase = A  + (m0 + srow) * (size_t)DD + schk * 8;
    const float* Bbase = Bm + (size_t)srow * DD + schk * 8;
    short* As_w = As + srow * LDT + schk * 8;
    short* Bs_w = Bs + srow * LDT + schk * 8;

    f32x4 acc[4][4];
    #pragma unroll
    for (int i = 0; i < 4; i++)
        #pragma unroll
        for (int j = 0; j < 4; j++) acc[i][j] = (f32x4)0.f;

    for (int kt = 0; kt < DD / BK; kt++) {
        const int k0 = kt * BK;
        #pragma unroll
        for (int p = 0; p < 4; p++) {
            const float* ga = Abase + (size_t)(p * 32) * DD + k0;
            const float* gb = Bbase + (size_t)(p * 32) * DD + k0;
            f32x4 a0 = *(const f32x4*)(ga);
            f32x4 a1 = *(const f32x4*)(ga + 4);
            f32x4 b0 = *(const f32x4*)(gb);
            f32x4 b1 = *(const f32x4*)(gb + 4);
            uint4 pa, pb;
            pa.x = pack_bf(a0.x, a0.y);  pa.y = pack_bf(a0.z, a0.w);
            pa.z = pack_bf(a1.x, a1.y);  pa.w = pack_bf(a1.z, a1.w);
            pb.x = pack_bf(b0.x, b0.y);  pb.y = pack_bf(b0.z, b0.w);
            pb.z = pack_bf(b1.x, b1.y);  pb.w = pack_bf(b1.z, b1.w);
            *(uint4*)(As_w + p * 32 * LDT) = pa;
            *(uint4*)(Bs_w + p * 32 * LDT) = pb;
        }
        __syncthreads();
        #pragma unroll
        for (int ks = 0; ks < 2; ks++) {
            const int ko = ks * 32 + quad * 8;
            s16x8 af[4], bf[4];
            #pragma unroll
            for (int i = 0; i < 4; i++)
                af[i] = *(const s16x8*)(As + (wm + i * 16 + ln15) * LDT + ko);
            #pragma unroll
            for (int j = 0; j < 4; j++)
                bf[j] = *(const s16x8*)(Bs + (wn + j * 16 + ln15) * LDT + ko);
            #pragma unroll
            for (int i = 0; i < 4; i++)
                #pragma unroll
                for (int j = 0; j < 4; j++)
                    acc[i][j] = __builtin_amdgcn_mfma_f32_16x16x32_bf16(af[i], bf[j], acc[i][j], 0, 0, 0);
        }
        __syncthreads();
    }

    // ---- fused epilogue: JSD terms, masked ----
    const int num_nodes = nn_lens[0];
    const int len_b     = nn_lens[1 + b_idx];
    const float LOG2f = 0.6931471805599453f;

    float pos_sum = 0.f, neg_sum = 0.f;
    #pragma unroll
    for (int i = 0; i < 4; i++) {
        #pragma unroll
        for (int r = 0; r < 4; r++) {
            const int s = s_base + wm + i * 16 + quad * 4 + r;       // C/D row = quad*4+reg
            const bool valid = (s < len_b);
            #pragma unroll
            for (int j = 0; j < 4; j++) {
                const int n = wn + j * 16 + ln15;                    // C/D col = lane&15
                const float x = acc[i][j][r];
                const float e  = __expf(-fabsf(x));
                const float sp = fmaxf(-x, 0.f) + __logf(1.f + e);   // softplus(-x), stable
                if (valid) {
                    if (n == b_idx) pos_sum += LOG2f - sp;           // Ep
                    else            neg_sum += sp + x - LOG2f;       // Eq
                }
            }
        }
    }

    // block reduction + one atomic per block
    #pragma unroll
    for (int off = 32; off > 0; off >>= 1) {
        pos_sum += __shfl_down(pos_sum, off, 64);
        neg_sum += __shfl_down(neg_sum, off, 64);
    }
    __syncthreads();                     // LDS tiles no longer needed
    __shared__ float red[8];
    if (lane == 0) { red[wid] = pos_sum; red[4 + wid] = neg_sum; }
    __syncthreads();
    if (tid == 0) {
        const float p  = red[0] + red[1] + red[2] + red[3];
        const float ng = red[4] + red[5] + red[6] + red[7];
        const float nn = (float)num_nodes;
        const float contrib = ng / (nn * (float)(BB - 1)) - p / nn;
        atomicAdd(out, contrib);
    }
}

extern "C" void kernel_launch(void* const* d_in, const int* in_sizes, int n_in,
                              void* d_out, int out_size, void* d_ws, size_t ws_size,
                              hipStream_t stream) {
    const float* seq  = (const float*)d_in[0];   // [128,1024,1024] fp32
    const float* ctx  = (const float*)d_in[1];   // [128,1024] fp32
    const int*   mask = (const int*)d_in[2];     // [128,1024] int32
    int* nn_lens = (int*)d_ws;                   // [0]=num_nodes, [1..128]=lens

    hipMemsetAsync(d_out, 0, sizeof(float), stream);
    hipMemsetAsync(d_ws, 0, sizeof(int), stream);

    lens_kernel<<<BB, 256, 0, stream>>>(mask, nn_lens);
    mi_kernel<<<(BB * SS) / MT, 256, 0, stream>>>(seq, ctx, nn_lens, (float*)d_out);
}